// Round 2
// baseline (9820.007 us; speedup 1.0000x reference)
//
#include <hip/hip_runtime.h>
#include <hip/hip_bf16.h>

// ---------------------------------------------------------------------------
// LSTM  T=1024 B=64 IN=128 H=1024 OUT=128
// Round 2 (= Round 1 resubmit; GPU acquisition timed out, kernel never ran).
// Correctness-anchor multi-launch version.
//   - bf16 MFMA (16x16x32), f32 accum, f32 cell state
//   - per step: 256 gate-WGs (batch16 x units16, K=1152=[h|x]) + 32 out-WGs
//   - out(t-1) computed in launch t from h(t-1) (kernel-boundary coherence)
// ---------------------------------------------------------------------------

using bf16x8 = __attribute__((ext_vector_type(8))) __bf16;
using f32x4  = __attribute__((ext_vector_type(4))) float;

__device__ __forceinline__ unsigned short f2bf(float f) {
    unsigned u = __builtin_bit_cast(unsigned, f);
    u = (u + 0x7FFFu + ((u >> 16) & 1u)) >> 16;
    return (unsigned short)u;
}

// ws layout (bytes)
#define OFF_XBF   0u            // [1024][64][128] bf16 : 16777216
#define OFF_WCAT  16777216u     // [4096][1152] bf16    :  9437184  (k<1024: W_hh, k>=1024: W_ih)
#define OFF_WOUT  26214400u     // [128][1024] bf16     :   262144
#define OFF_BSUM  26476544u     // [4096] f32           :    16384  (b_ih+b_hh)
#define OFF_HBUF  26492928u     // [2][64][1024] bf16   :   262144
#define OFF_CST   26755072u     // [64][1024] f32       :   262144
// total 27017216

__global__ __launch_bounds__(256) void lstm_prep(
    const float* __restrict__ in_seq, const float* __restrict__ h0,
    const float* __restrict__ c0,     const float* __restrict__ W_ih,
    const float* __restrict__ W_hh,   const float* __restrict__ b_ih,
    const float* __restrict__ b_hh,   const float* __restrict__ W_out,
    unsigned short* __restrict__ xbf, unsigned short* __restrict__ wcat,
    unsigned short* __restrict__ woutb, float* __restrict__ bsum,
    unsigned short* __restrict__ hbuf, float* __restrict__ cstate)
{
    for (size_t i = (size_t)blockIdx.x * blockDim.x + threadIdx.x;
         i < 13373440u; i += (size_t)gridDim.x * blockDim.x) {
        if (i < 8388608u) {
            xbf[i] = f2bf(in_seq[i]);
        } else if (i < 13107200u) {
            size_t j = i - 8388608u;
            size_t r = j / 1152u, k = j - r * 1152u;
            float v = (k < 1024u) ? W_hh[r * 1024u + k] : W_ih[r * 128u + (k - 1024u)];
            wcat[j] = f2bf(v);
        } else if (i < 13238272u) {
            size_t j = i - 13107200u;
            woutb[j] = f2bf(W_out[j]);
        } else if (i < 13242368u) {
            size_t j = i - 13238272u;
            bsum[j] = b_ih[j] + b_hh[j];
        } else if (i < 13307904u) {
            size_t j = i - 13242368u;
            hbuf[j] = f2bf(h0[j]);           // read-buffer for t=0 is hbuf[0]
        } else {
            size_t j = i - 13307904u;
            cstate[j] = c0[j];
        }
    }
}

__global__ __launch_bounds__(256) void lstm_step(
    const unsigned short* __restrict__ xbf,   // [1024][64][128]
    const unsigned short* __restrict__ wcat,  // [4096][1152]
    const unsigned short* __restrict__ woutb, // [128][1024]
    const float* __restrict__ bsum,           // [4096]
    const float* __restrict__ bout,           // [128]
    unsigned short* __restrict__ hbuf,        // [2][64][1024]
    float* __restrict__ cstate,               // [64][1024]
    float* __restrict__ out,                  // [1024][64][128]
    int t)
{
    __shared__ float red[4096];               // 16 KiB reduce buffer
    const int tid = threadIdx.x;
    const int w   = tid >> 6;                 // wave 0..3
    const int l   = tid & 63;                 // lane
    const int l4  = l >> 4;                   // 0..3
    const int l15 = l & 15;
    const int rb  = t & 1;                    // read h(t-1) from hbuf[rb]
    const int wb  = rb ^ 1;                   // write h(t) to hbuf[wb]

    if (blockIdx.x < 256) {
        // ---------------- gate WG: batch [16p,16p+16), units [16q,16q+16) --------
        if (t >= 1024) return;
        const int p = blockIdx.x >> 6;
        const int q = blockIdx.x & 63;
        const int arow = 16 * p + l15;        // A-fragment row (batch)

        const unsigned short* hrow = hbuf + (size_t)rb * 65536u + (size_t)arow * 1024u;
        const unsigned short* xrow = xbf + ((size_t)t * 64u + arow) * 128u;
        // B rows (gate columns): gate g, unit col l15 -> W row g*1024 + 16q + l15
        const unsigned short* wrow0 = wcat + (size_t)(16 * q + l15) * 1152u;

        f32x4 acc0 = {0.f, 0.f, 0.f, 0.f}, acc1 = acc0, acc2 = acc0, acc3 = acc0;
        const int kbase = w * 288;            // wave-level split-K

#pragma unroll
        for (int kk = 0; kk < 9; ++kk) {
            const int k0   = kbase + kk * 32;
            const int koff = k0 + l4 * 8;
            bf16x8 a;
            if (k0 < 1024) a = *(const bf16x8*)(hrow + koff);
            else           a = *(const bf16x8*)(xrow + (koff - 1024));
            const size_t wo = (size_t)koff;
            bf16x8 b0 = *(const bf16x8*)(wrow0 + wo);
            bf16x8 b1 = *(const bf16x8*)(wrow0 + wo + 1024u * 1152u);
            bf16x8 b2 = *(const bf16x8*)(wrow0 + wo + 2048u * 1152u);
            bf16x8 b3 = *(const bf16x8*)(wrow0 + wo + 3072u * 1152u);
            acc0 = __builtin_amdgcn_mfma_f32_16x16x32_bf16(a, b0, acc0, 0, 0, 0);
            acc1 = __builtin_amdgcn_mfma_f32_16x16x32_bf16(a, b1, acc1, 0, 0, 0);
            acc2 = __builtin_amdgcn_mfma_f32_16x16x32_bf16(a, b2, acc2, 0, 0, 0);
            acc3 = __builtin_amdgcn_mfma_f32_16x16x32_bf16(a, b3, acc3, 0, 0, 0);
        }

        // cross-wave split-K reduce. slot s = D reg index (batch row 4*l4+s).
        // XOR swizzle keeps b128 accesses conflict-free; a16 in 16B units.
#pragma unroll
        for (int s = 0; s < 4; ++s) {
            f32x4 vv = {acc0[s], acc1[s], acc2[s], acc3[s]};   // (i,f,g,o) partial
            const int a16 = s * 256 + (((l * 4) + w) ^ (l & 7));
            *(f32x4*)((char*)red + (size_t)a16 * 16u) = vv;
        }
        __syncthreads();

        f32x4 gv = {0.f, 0.f, 0.f, 0.f};
#pragma unroll
        for (int v = 0; v < 4; ++v) {
            const int a16 = w * 256 + (((l * 4) + v) ^ (l & 7));
            gv += *(const f32x4*)((const char*)red + (size_t)a16 * 16u);
        }

        const int u = 16 * q + l15;           // global hidden unit
        const int b = 16 * p + 4 * l4 + w;    // global batch row
        float gi = gv[0] + bsum[u];
        float gf = gv[1] + bsum[1024 + u];
        float gg = gv[2] + bsum[2048 + u];
        float go = gv[3] + bsum[3072 + u];
        float i_ = 1.f / (1.f + __expf(-gi));
        float f_ = 1.f / (1.f + __expf(-gf));
        float g_ = 1.f - 2.f / (__expf(2.f * gg) + 1.f);
        float o_ = 1.f / (1.f + __expf(-go));
        float c  = cstate[b * 1024 + u];
        float cn = f_ * c + i_ * g_;
        cstate[b * 1024 + u] = cn;
        float th = 1.f - 2.f / (__expf(2.f * cn) + 1.f);
        hbuf[(size_t)wb * 65536u + (size_t)b * 1024u + u] = f2bf(o_ * th);
    } else {
        // ---------------- out WG: out(t-1) = h(t-1) @ W_out^T + b_out ------------
        if (t < 1) return;
        const int j = blockIdx.x - 256;
        const int p = j >> 3;                 // batch group
        const int n = j & 7;                  // out-col tile
        const unsigned short* hrow = hbuf + (size_t)rb * 65536u + (size_t)(16 * p + l15) * 1024u;
        const unsigned short* wrow = woutb + (size_t)(16 * n + l15) * 1024u;

        f32x4 acc = {0.f, 0.f, 0.f, 0.f};
#pragma unroll
        for (int kk = 0; kk < 8; ++kk) {
            const int koff = w * 256 + kk * 32 + l4 * 8;
            bf16x8 a  = *(const bf16x8*)(hrow + koff);
            bf16x8 bb = *(const bf16x8*)(wrow + koff);
            acc = __builtin_amdgcn_mfma_f32_16x16x32_bf16(a, bb, acc, 0, 0, 0);
        }
#pragma unroll
        for (int s = 0; s < 4; ++s) {
            const int a16 = s * 256 + (((l * 4) + w) ^ (l & 7));
            ((float*)red)[(size_t)a16 * 4u] = acc[s];
        }
        __syncthreads();
        float sum = 0.f;
#pragma unroll
        for (int v = 0; v < 4; ++v) {
            const int a16 = w * 256 + (((l * 4) + v) ^ (l & 7));
            sum += ((const float*)red)[(size_t)a16 * 4u];
        }
        const int o = 16 * n + l15;
        const int b = 16 * p + 4 * l4 + w;
        out[((size_t)(t - 1) * 64u + b) * 128u + o] = sum + bout[o];
    }
}

extern "C" void kernel_launch(void* const* d_in, const int* in_sizes, int n_in,
                              void* d_out, int out_size, void* d_ws, size_t ws_size,
                              hipStream_t stream) {
    const float* in_seq = (const float*)d_in[0];
    const float* h0     = (const float*)d_in[1];
    const float* c0     = (const float*)d_in[2];
    const float* W_ih   = (const float*)d_in[3];
    const float* W_hh   = (const float*)d_in[4];
    const float* b_ih   = (const float*)d_in[5];
    const float* b_hh   = (const float*)d_in[6];
    const float* W_out  = (const float*)d_in[7];
    const float* b_out  = (const float*)d_in[8];

    char* ws = (char*)d_ws;
    unsigned short* xbf   = (unsigned short*)(ws + OFF_XBF);
    unsigned short* wcat  = (unsigned short*)(ws + OFF_WCAT);
    unsigned short* woutb = (unsigned short*)(ws + OFF_WOUT);
    float*          bsum  = (float*)(ws + OFF_BSUM);
    unsigned short* hbuf  = (unsigned short*)(ws + OFF_HBUF);
    float*          cst   = (float*)(ws + OFF_CST);
    float*          out   = (float*)d_out;

    lstm_prep<<<2048, 256, 0, stream>>>(in_seq, h0, c0, W_ih, W_hh, b_ih, b_hh,
                                        W_out, xbf, wcat, woutb, bsum, hbuf, cst);
    for (int t = 0; t <= 1024; ++t) {
        lstm_step<<<288, 256, 0, stream>>>(xbf, wcat, woutb, bsum, b_out,
                                           hbuf, cst, out, t);
    }
}